// Round 1
// baseline (693.894 us; speedup 1.0000x reference)
//
#include <hip/hip_runtime.h>

#define ZD 21
#define YD 256
#define XD 256
#define BD 2
#define NCIN 16
#define NC1 32
#define NC2 64
#define BN_EPS 1e-3f

__global__ __launch_bounds__(256) void scatter_grid_k(const int* __restrict__ coors,
                                                      int* __restrict__ grid, int n) {
    int i = blockIdx.x * 256 + threadIdx.x;
    if (i >= n) return;
    const int4 c = ((const int4*)coors)[i];   // [b, z, y, x]
    const int lin = ((c.x * ZD + c.y) * YD + c.z) * XD + c.w;
    grid[lin] = i;
}

__global__ __launch_bounds__(256) void conv1_k(
    const float* __restrict__ feat, const int* __restrict__ coors,
    const float* __restrict__ W1,
    const float* __restrict__ g1, const float* __restrict__ b1,
    const float* __restrict__ m1, const float* __restrict__ v1,
    const int* __restrict__ grid, float* __restrict__ f1, int n) {
    int i = blockIdx.x * 256 + threadIdx.x;
    if (i >= n) return;
    const int4 cc = ((const int4*)coors)[i];
    const int b = cc.x, z0 = cc.y, y0 = cc.z, x0 = cc.w;
    float acc[NC1];
#pragma unroll
    for (int c = 0; c < NC1; ++c) acc[c] = 0.f;

#pragma unroll 1
    for (int k = 0; k < 27; ++k) {
        const int dz = k / 9 - 1, dy = (k / 3) % 3 - 1, dx = k % 3 - 1;
        const int z = z0 + dz, y = y0 + dy, x = x0 + dx;
        if ((unsigned)z >= (unsigned)ZD || (unsigned)y >= (unsigned)YD ||
            (unsigned)x >= (unsigned)XD) continue;
        const int idx = grid[((b * ZD + z) * YD + y) * XD + x];
        if (idx < 0) continue;
        const float* __restrict__ fp = feat + (size_t)idx * NCIN;
        const float* __restrict__ wk = W1 + k * (NCIN * NC1);
#pragma unroll
        for (int ci = 0; ci < NCIN; ci += 4) {
            const float4 f = *(const float4*)(fp + ci);
            const float* w = wk + ci * NC1;
#pragma unroll
            for (int c = 0; c < NC1; ++c) {
                float a = acc[c];
                a += f.x * w[c];
                a += f.y * w[NC1 + c];
                a += f.z * w[2 * NC1 + c];
                a += f.w * w[3 * NC1 + c];
                acc[c] = a;
            }
        }
    }
    float* __restrict__ op = f1 + (size_t)i * NC1;
#pragma unroll
    for (int c = 0; c < NC1; ++c) {
        const float s = g1[c] * rsqrtf(v1[c] + BN_EPS);
        const float o = (acc[c] - m1[c]) * s + b1[c];
        op[c] = fmaxf(o, 0.f);
    }
}

__global__ __launch_bounds__(256) void conv2_k(
    const float* __restrict__ f1, const int* __restrict__ ocoors,
    const float* __restrict__ W2,
    const float* __restrict__ g2, const float* __restrict__ b2,
    const float* __restrict__ m2, const float* __restrict__ v2,
    const int* __restrict__ grid, float* __restrict__ out, int m) {
    int i = blockIdx.x * 256 + threadIdx.x;
    if (i >= m) return;
    const int4 cc = ((const int4*)ocoors)[i];
    const int b = cc.x, oz = cc.y, oy = cc.z, ox = cc.w;
    float acc[NC2];
#pragma unroll
    for (int c = 0; c < NC2; ++c) acc[c] = 0.f;

#pragma unroll 1
    for (int k = 0; k < 27; ++k) {
        const int jz = k / 9, jy = (k / 3) % 3, jx = k % 3;
        const int z = oz * 2 + jz;          // pad_z = 0
        const int y = oy * 2 - 1 + jy;      // pad_y = 1
        const int x = ox * 2 - 1 + jx;      // pad_x = 1
        if ((unsigned)z >= (unsigned)ZD || (unsigned)y >= (unsigned)YD ||
            (unsigned)x >= (unsigned)XD) continue;
        const int idx = grid[((b * ZD + z) * YD + y) * XD + x];
        if (idx < 0) continue;
        const float* __restrict__ fp = f1 + (size_t)idx * NC1;
        const float* __restrict__ wk = W2 + k * (NC1 * NC2);
#pragma unroll 2
        for (int ci = 0; ci < NC1; ci += 4) {
            const float4 f = *(const float4*)(fp + ci);
            const float* w = wk + ci * NC2;
#pragma unroll
            for (int c = 0; c < NC2; ++c) {
                float a = acc[c];
                a += f.x * w[c];
                a += f.y * w[NC2 + c];
                a += f.z * w[2 * NC2 + c];
                a += f.w * w[3 * NC2 + c];
                acc[c] = a;
            }
        }
    }
    float* __restrict__ op = out + (size_t)i * NC2;
#pragma unroll
    for (int c = 0; c < NC2; ++c) {
        const float s = g2[c] * rsqrtf(v2[c] + BN_EPS);
        const float o = (acc[c] - m2[c]) * s + b2[c];
        op[c] = fmaxf(o, 0.f);
    }
}

// out_coors passthrough (as float values) + batch_size
__global__ __launch_bounds__(256) void tail_k(const int* __restrict__ oc,
                                              const int* __restrict__ bs,
                                              float* __restrict__ out, int m4) {
    int i = blockIdx.x * 256 + threadIdx.x;
    if (i < m4) out[i] = (float)oc[i];
    if (i == m4) out[m4] = (float)bs[0];
}

extern "C" void kernel_launch(void* const* d_in, const int* in_sizes, int n_in,
                              void* d_out, int out_size, void* d_ws, size_t ws_size,
                              hipStream_t stream) {
    const float* feat  = (const float*)d_in[0];
    const int*   coors = (const int*)d_in[1];
    const int*   ocoors= (const int*)d_in[2];
    const float* W1 = (const float*)d_in[3];
    const float* g1 = (const float*)d_in[4];
    const float* b1 = (const float*)d_in[5];
    const float* m1 = (const float*)d_in[6];
    const float* v1 = (const float*)d_in[7];
    const float* W2 = (const float*)d_in[8];
    const float* g2 = (const float*)d_in[9];
    const float* b2 = (const float*)d_in[10];
    const float* m2 = (const float*)d_in[11];
    const float* v2 = (const float*)d_in[12];
    const int*   bs = (const int*)d_in[13];

    const int n = in_sizes[0] / NCIN;
    const int m = in_sizes[2] / 4;

    const size_t GRID_N = (size_t)BD * ZD * YD * XD;
    int* grid = (int*)d_ws;
    float* f1 = (float*)((char*)d_ws + ((GRID_N * sizeof(int) + 255) & ~(size_t)255));

    hipMemsetAsync(grid, 0xFF, GRID_N * sizeof(int), stream);
    scatter_grid_k<<<(n + 255) / 256, 256, 0, stream>>>(coors, grid, n);
    conv1_k<<<(n + 255) / 256, 256, 0, stream>>>(feat, coors, W1, g1, b1, m1, v1, grid, f1, n);

    float* out = (float*)d_out;
    conv2_k<<<(m + 255) / 256, 256, 0, stream>>>(f1, ocoors, W2, g2, b2, m2, v2, grid, out, m);
    tail_k<<<(m * 4 + 1 + 255) / 256, 256, 0, stream>>>(ocoors, bs, out + (size_t)m * NC2, m * 4);
}